// Round 7
// baseline (214.619 us; speedup 1.0000x reference)
//
#include <hip/hip_runtime.h>
#include <hip/hip_bf16.h>

#define NB    16
#define NPT   4096
#define NSRC  1024
#define ND1   128
#define ND2   256
#define NCIN  384
#define NCMID 256
#define NCOUT 128
#define BNTOT (NB * NPT)   // 65536 points
#define BN_EPS 1e-5f

typedef float f32x4 __attribute__((ext_vector_type(4)));
typedef short bf16x8 __attribute__((ext_vector_type(8)));
typedef unsigned int uint;

union PK8 { unsigned short u[8]; uint4 q; };
union PK4 { unsigned short u[4]; uint2 q; };

static __device__ __forceinline__ unsigned short f2bf(float f) {
  __hip_bfloat16 h = __float2bfloat16(f);
  return __builtin_bit_cast(unsigned short, h);
}
static __device__ __forceinline__ float bf2f(unsigned short u) {
  return __builtin_bit_cast(float, (uint)u << 16);
}
static __device__ __forceinline__ void gl_lds16(const unsigned short* g, unsigned short* l) {
  __builtin_amdgcn_global_load_lds(
      (const __attribute__((address_space(1))) uint*)(const void*)g,
      (__attribute__((address_space(3))) uint*)(void*)l,
      16, 0, 0);
}

#if __has_builtin(__builtin_amdgcn_fmed3f)
#define MED3F(a, b, c) __builtin_amdgcn_fmed3f((a), (b), (c))
#else
#define MED3F(a, b, c) fmaxf((a), fminf((b), (c)))
#endif

// total order: (d, idx) with ties -> lower index (matches lax.top_k)
static __device__ __forceinline__ bool prec(float da, int ia, float db, int ib) {
  return (da < db) || (da == db && ia < ib);
}

// shallow branchless top-3 insert (proven rounds 5/6)
#define INSV(t0, t1, t2, j0, j1, j2, d, idx)                                   \
  {                                                                            \
    const bool c0 = (d) < t0;                                                  \
    const bool c1 = (d) < t1;                                                  \
    const bool c2 = (d) < t2;                                                  \
    const float m1 = MED3F(t0, t1, (d));                                       \
    const float m2 = fminf(t2, fmaxf(t1, (d)));                                \
    t0 = fminf(t0, (d));                                                       \
    j2 = c2 ? (c1 ? j1 : (idx)) : j2;                                          \
    j1 = c1 ? (c0 ? j0 : (idx)) : j1;                                          \
    j0 = c0 ? (idx) : j0;                                                      \
    t1 = m1; t2 = m2;                                                          \
  }

#define MERGE3(d0, j0, d1, j1, d2, j2, e0, i0, e1, i1, e2, i2)                 \
  {                                                                            \
    const bool p0 = prec(d0, j0, e0, i0);                                      \
    const float l0d = p0 ? e0 : d0; const int l0j = p0 ? i0 : j0;              \
    const float r0d = p0 ? d0 : e0; const int r0j = p0 ? j0 : i0;              \
    const bool p1 = prec(d1, j1, e1, i1);                                      \
    const float w1d = p1 ? d1 : e1; const int w1j = p1 ? j1 : i1;              \
    const bool pr1 = prec(l0d, l0j, w1d, w1j);                                 \
    const float r1d = pr1 ? l0d : w1d; const int r1j = pr1 ? l0j : w1j;        \
    const float q1d = pr1 ? w1d : l0d; const int q1j = pr1 ? w1j : l0j;        \
    const bool p2 = prec(d2, j2, e2, i2);                                      \
    const float w2d = p2 ? d2 : e2; const int w2j = p2 ? j2 : i2;              \
    const bool pr2 = prec(q1d, q1j, w2d, w2j);                                 \
    const float r2d = pr2 ? q1d : w2d; const int r2j = pr2 ? q1j : w2j;        \
    d0 = r0d; j0 = r0j; d1 = r1d; j1 = r1j; d2 = r2d; j2 = r2j;                \
  }

// ---------------- prep: W1,W2 fp32 -> bf16 ----------------
__global__ __launch_bounds__(256) void prep_w_kernel(
    const float* __restrict__ w1, const float* __restrict__ w2,
    unsigned short* __restrict__ w1b, unsigned short* __restrict__ w2b)
{
  const int i = blockIdx.x * 256 + threadIdx.x;
  const bool isW1 = i < 24576;
  const float4 v = isW1 ? ((const float4*)w1)[i] : ((const float4*)w2)[i - 24576];
  PK4 pk;
  pk.u[0] = f2bf(v.x); pk.u[1] = f2bf(v.y); pk.u[2] = f2bf(v.z); pk.u[3] = f2bf(v.w);
  if (isW1) ((uint2*)w1b)[i] = pk.q;
  else      ((uint2*)w2b)[i - 24576] = pk.q;
}

// ============ fg1 v2: wave-independent kNN + interp + GEMM1 + BN1 partials ============
// 256 threads (4 waves), 64 pts/block, grid 1024. One barrier after s2t staging;
// afterwards each wave is fully independent: knn(16 pts) -> 12-kt MFMA loop with
// A built in registers (points1 cast / 3-NN gather) and B loaded global->reg (L2).
__global__ __launch_bounds__(256, 3) void fg1_kernel(
    const float* __restrict__ xyz1, const float* __restrict__ xyz2,
    const float* __restrict__ points1, const float* __restrict__ points2,
    const unsigned short* __restrict__ W1bf, const float* __restrict__ bias1,
    unsigned short* __restrict__ h1bf, float* __restrict__ pS, float* __restrict__ pQ)
{
  __shared__ float4 s2t[4 * 257];             // 16.4 KB transformed xyz2
  __shared__ int   sj[64][3];
  __shared__ float sw[64][3];
  __shared__ float redS[4][256];
  __shared__ float redQ[4][256];

  const int tid = threadIdx.x;
  const int lane = tid & 63;
  const int wave = tid >> 6;
  const int ptBase = blockIdx.x * 64;
  const int b = ptBase >> 12;                 // 64 blocks per batch, no straddle

  { // stage + transform xyz2: thread t covers sources 4t..4t+3
    const float* src = xyz2 + (size_t)b * NSRC * 3 + tid * 12;
    const float4 l0 = ((const float4*)src)[0];
    const float4 l1 = ((const float4*)src)[1];
    const float4 l2 = ((const float4*)src)[2];
    const float xs[4] = {l0.x, l0.w, l1.z, l2.y};
    const float ys[4] = {l0.y, l1.x, l1.w, l2.z};
    const float zs[4] = {l0.z, l1.y, l2.x, l2.w};
    const int qq = tid >> 6;
    const int ibase = (tid & 63) * 4;
#pragma unroll
    for (int u = 0; u < 4; ++u) {
      const float c = xs[u] * xs[u] + ys[u] * ys[u] + zs[u] * zs[u];
      float4 v;
      v.x = -2.0f * xs[u]; v.y = -2.0f * ys[u]; v.z = -2.0f * zs[u]; v.w = c;
      s2t[qq * 257 + ibase + u] = v;
    }
  }
  __syncthreads();   // the ONLY block-wide barrier before the epilogue

  // ---- per-wave kNN for its 16 points (proven core, 4 lanes/pt) ----
  {
    const int ptl = wave * 16 + (lane >> 2);  // 0..63 local point
    const int q = lane & 3;
    const int p = ptBase + ptl;
    const float ax = xyz1[(size_t)p * 3 + 0];
    const float ay = xyz1[(size_t)p * 3 + 1];
    const float az = xyz1[(size_t)p * 3 + 2];
    const float a2 = ax * ax + ay * ay + az * az;
    const float4* slab = &s2t[q * 257];
    const int qbase = q * 256;

    const float INF = 3.4e38f;
    float ta0 = INF, ta1 = INF, ta2 = INF; int ja0 = 0, ja1 = 0, ja2 = 0;
    float tb0 = INF, tb1 = INF, tb2 = INF; int jb0 = 0, jb1 = 0, jb2 = 0;

    for (int i = 0; i < 256; i += 2) {
      const float4 va = slab[i];
      float da = va.w + a2;
      da = fmaf(va.x, ax, da); da = fmaf(va.y, ay, da); da = fmaf(va.z, az, da);
      INSV(ta0, ta1, ta2, ja0, ja1, ja2, da, qbase + i);
      const float4 vb = slab[i + 1];
      float db = vb.w + a2;
      db = fmaf(vb.x, ax, db); db = fmaf(vb.y, ay, db); db = fmaf(vb.z, az, db);
      INSV(tb0, tb1, tb2, jb0, jb1, jb2, db, qbase + i + 1);
    }
    MERGE3(ta0, ja0, ta1, ja1, ta2, ja2, tb0, jb0, tb1, jb1, tb2, jb2);

#pragma unroll
    for (int m = 1; m <= 2; m <<= 1) {
      float e0 = __shfl_xor(ta0, m), e1 = __shfl_xor(ta1, m), e2 = __shfl_xor(ta2, m);
      int i0 = __shfl_xor(ja0, m), i1 = __shfl_xor(ja1, m), i2 = __shfl_xor(ja2, m);
      MERGE3(ta0, ja0, ta1, ja1, ta2, ja2, e0, i0, e1, i1, e2, i2);
    }

    if (q == 0) {   // wave-coherent LDS write; read later by SAME wave only
      float w0 = 1.f / (ta0 + 1e-8f), w1 = 1.f / (ta1 + 1e-8f), w2 = 1.f / (ta2 + 1e-8f);
      const float inv = 1.f / (w0 + w1 + w2);
      sj[ptl][0] = ja0; sj[ptl][1] = ja1; sj[ptl][2] = ja2;
      sw[ptl][0] = w0 * inv; sw[ptl][1] = w1 * inv; sw[ptl][2] = w2 * inv;
    }
  }

  // ---- per-wave K-loop: A in regs, B global->reg, 16 MFMA/kt, no barriers ----
  const int fr = lane & 15;
  const int cs = lane >> 4;
  const int wrow = wave * 16 + fr;            // this lane's A row (local)
  const int pA = ptBase + wrow;               // global point for A row

  // gather metadata for row wrow (same-wave LDS RAW, ordered by lgkmcnt)
  const int gj0 = sj[wrow][0], gj1 = sj[wrow][1], gj2 = sj[wrow][2];
  const float gw0 = sw[wrow][0], gw1 = sw[wrow][1], gw2 = sw[wrow][2];
  const float* p2base = points2 + (size_t)b * NSRC * ND2;
  const float* r0p = p2base + (size_t)gj0 * ND2;
  const float* r1p = p2base + (size_t)gj1 * ND2;
  const float* r2p = p2base + (size_t)gj2 * ND2;

  f32x4 acc[16];
#pragma unroll
  for (int j = 0; j < 16; ++j)
#pragma unroll
    for (int q = 0; q < 4; ++q) acc[j][q] = 0.0f;

  for (int kt = 0; kt < 12; ++kt) {
    const int k = kt * 32 + cs * 8;
    // --- A fragment (row wrow, k..k+8) in registers ---
    PK8 af;
    if (kt < 4) {
      const float* src = points1 + (size_t)pA * ND1 + k;
      const float4 va = ((const float4*)src)[0];
      const float4 vb = ((const float4*)src)[1];
      af.u[0] = f2bf(va.x); af.u[1] = f2bf(va.y); af.u[2] = f2bf(va.z); af.u[3] = f2bf(va.w);
      af.u[4] = f2bf(vb.x); af.u[5] = f2bf(vb.y); af.u[6] = f2bf(vb.z); af.u[7] = f2bf(vb.w);
    } else {
      const int ko = k - ND1;
      const float4* g0 = (const float4*)(r0p + ko);
      const float4* g1 = (const float4*)(r1p + ko);
      const float4* g2 = (const float4*)(r2p + ko);
#pragma unroll
      for (int h = 0; h < 2; ++h) {
        const float4 va = g0[h], vb = g1[h], vc = g2[h];
        af.u[h * 4 + 0] = f2bf(gw0 * va.x + gw1 * vb.x + gw2 * vc.x);
        af.u[h * 4 + 1] = f2bf(gw0 * va.y + gw1 * vb.y + gw2 * vc.y);
        af.u[h * 4 + 2] = f2bf(gw0 * va.z + gw1 * vb.z + gw2 * vc.z);
        af.u[h * 4 + 3] = f2bf(gw0 * va.w + gw1 * vb.w + gw2 * vc.w);
      }
    }
    const bf16x8 a = __builtin_bit_cast(bf16x8, af.q);
    // --- B fragments direct from global (L2-resident W1bf), 2 groups of 8 ---
#pragma unroll
    for (int g = 0; g < 2; ++g) {
      uint4 bq[8];
#pragma unroll
      for (int jj = 0; jj < 8; ++jj) {
        const int j = g * 8 + jj;
        bq[jj] = *(const uint4*)(W1bf + (size_t)(j * 16 + fr) * NCIN + k);
      }
#pragma unroll
      for (int jj = 0; jj < 8; ++jj) {
        const bf16x8 bv = __builtin_bit_cast(bf16x8, bq[jj]);
        acc[g * 8 + jj] = __builtin_amdgcn_mfma_f32_16x16x32_bf16(a, bv, acc[g * 8 + jj], 0, 0, 0);
      }
    }
  }

  // ---- epilogue: h1bf store + BN1 partial sums (per-block, no atomics) ----
  const int r0 = cs * 4;
#pragma unroll
  for (int j = 0; j < 16; ++j) {
    const int ch = j * 16 + fr;
    const float bb = bias1[ch];
    float s = 0.f, s2 = 0.f;
#pragma unroll
    for (int q = 0; q < 4; ++q) {
      const int pt = ptBase + wave * 16 + r0 + q;
      const float v = acc[j][q] + bb;
      h1bf[(size_t)pt * NCMID + ch] = f2bf(v);
      s += v; s2 += v * v;
    }
    s += __shfl_xor(s, 16);  s2 += __shfl_xor(s2, 16);
    s += __shfl_xor(s, 32);  s2 += __shfl_xor(s2, 32);
    if (cs == 0) { redS[wave][ch] = s; redQ[wave][ch] = s2; }
  }
  __syncthreads();
  {
    const int ch = tid;   // 256 threads = 256 channels
    const float s  = redS[0][ch] + redS[1][ch] + redS[2][ch] + redS[3][ch];
    const float s2 = redQ[0][ch] + redQ[1][ch] + redQ[2][ch] + redQ[3][ch];
    pS[(size_t)blockIdx.x * NCMID + ch] = s;
    pQ[(size_t)blockIdx.x * NCMID + ch] = s2;
  }
}

// ---------------- reduce per-block BN1 partials (32 blocks -> atomics) ----------------
__global__ __launch_bounds__(256) void colred_kernel(
    const float* __restrict__ pS, const float* __restrict__ pQ,
    float* __restrict__ sum1, float* __restrict__ sq1)
{
  const int ch = threadIdx.x;
  const int r0 = blockIdx.x * 32;             // 32 rows of 1024
  float s = 0.f, s2 = 0.f;
  for (int i = 0; i < 32; ++i) {
    s  += pS[(size_t)(r0 + i) * NCMID + ch];
    s2 += pQ[(size_t)(r0 + i) * NCMID + ch];
  }
  atomicAdd(&sum1[ch], s);
  atomicAdd(&sq1[ch], s2);
}

// ---------------- fold BN into per-channel affine: y = a*x + d ----------------
template <int C>
__global__ void stats_kernel(const float* __restrict__ sum, const float* __restrict__ sumsq,
                             const float* __restrict__ g, const float* __restrict__ be,
                             float* __restrict__ a, float* __restrict__ d)
{
  const int c = threadIdx.x;
  const float mean = sum[c] * (1.0f / BNTOT);
  const float var = sumsq[c] * (1.0f / BNTOT) - mean * mean;
  const float inv = rsqrtf(var + BN_EPS);
  const float ac = g[c] * inv;
  a[c] = ac;
  d[c] = be[c] - mean * ac;
}

// ---------------- GEMM2 (+fused BN2 column sums, bf16 out) — proven round 5/6 ----------------
__global__ __launch_bounds__(256, 2) void gemm2_kernel(
    const unsigned short* __restrict__ h1bf, const unsigned short* __restrict__ W2bf,
    const float* __restrict__ bias2, const float* __restrict__ aff_a,
    const float* __restrict__ aff_d, unsigned short* __restrict__ h2bf,
    float* __restrict__ sum2, float* __restrict__ sq2)
{
  __shared__ unsigned short sA[2][128][32];
  __shared__ unsigned short sB[2][128][32];
  __shared__ float sa[NCMID], sd[NCMID];
  const int tid = threadIdx.x;
  const int lane = tid & 63;
  const int wave = tid >> 6;
  const int ptBase = blockIdx.x * 128;
  sa[tid] = aff_a[tid];
  sd[tid] = aff_d[tid];

  f32x4 acc[2][8];
#pragma unroll
  for (int m = 0; m < 2; ++m)
#pragma unroll
    for (int j = 0; j < 8; ++j)
#pragma unroll
      for (int q = 0; q < 4; ++q) acc[m][j][q] = 0.0f;

  const int fr = lane & 15;
  const int cs = lane >> 4;
  const int rdsh = ((cs ^ ((fr >> 1) & 3)) << 3);

  auto stageB = [&](int buf, int kt) {
    const int k0 = kt * 32;
#pragma unroll
    for (int c = 0; c < 2; ++c) {
      const int s = c * 256 + wave * 64 + lane;
      const int row = s >> 2, c16 = s & 3;
      const int ks = c16 ^ ((row >> 1) & 3);
      gl_lds16(W2bf + (size_t)row * NCMID + k0 + ks * 8,
               &sB[buf][0][0] + (c * 256 + wave * 64) * 8);
    }
  };
  auto stageA = [&](int buf, int kt) {
    const int k0 = kt * 32;
#pragma unroll
    for (int c = 0; c < 2; ++c) {
      const int s = c * 256 + tid;
      const int row = s >> 2, c16 = s & 3;
      const int ks = c16 ^ ((row >> 1) & 3);
      const int k = k0 + ks * 8;
      PK8 v;
      v.q = *(const uint4*)(h1bf + (size_t)(ptBase + row) * NCMID + k);
      PK8 pk;
#pragma unroll
      for (int j = 0; j < 8; ++j)
        pk.u[j] = f2bf(fmaxf(0.f, sa[k + j] * bf2f(v.u[j]) + sd[k + j]));
      *(uint4*)(&sA[buf][0][0] + s * 8) = pk.q;
    }
  };

  stageB(0, 0);
  __syncthreads();
  stageA(0, 0);
  __syncthreads();
  int cur = 0;
  for (int kt = 0; kt < 8; ++kt) {
    if (kt < 7) { stageB(cur ^ 1, kt + 1); stageA(cur ^ 1, kt + 1); }
    const bf16x8 a0 = *(const bf16x8*)&sA[cur][wave * 32 + fr][rdsh];
    const bf16x8 a1 = *(const bf16x8*)&sA[cur][wave * 32 + 16 + fr][rdsh];
#pragma unroll
    for (int j = 0; j < 8; ++j) {
      const bf16x8 b = *(const bf16x8*)&sB[cur][j * 16 + fr][rdsh];
      acc[0][j] = __builtin_amdgcn_mfma_f32_16x16x32_bf16(a0, b, acc[0][j], 0, 0, 0);
      acc[1][j] = __builtin_amdgcn_mfma_f32_16x16x32_bf16(a1, b, acc[1][j], 0, 0, 0);
    }
    __syncthreads();
    cur ^= 1;
  }

  float* redS = (float*)&sA[0][0][0];
  float* redQ = redS + 512;
  const int col = fr;
  const int r0 = cs * 4;
#pragma unroll
  for (int j = 0; j < 8; ++j) {
    const int ch = j * 16 + col;
    const float bb = bias2[ch];
    float s = 0.f, s2 = 0.f;
#pragma unroll
    for (int m = 0; m < 2; ++m)
#pragma unroll
      for (int q = 0; q < 4; ++q) {
        const int pt = ptBase + wave * 32 + m * 16 + r0 + q;
        const float v = acc[m][j][q] + bb;
        h2bf[(size_t)pt * NCOUT + ch] = f2bf(v);
        s += v; s2 += v * v;
      }
    s += __shfl_xor(s, 16);  s2 += __shfl_xor(s2, 16);
    s += __shfl_xor(s, 32);  s2 += __shfl_xor(s2, 32);
    if (cs == 0) { redS[wave * 128 + fr * 8 + j] = s; redQ[wave * 128 + fr * 8 + j] = s2; }
  }
  __syncthreads();
  if (tid < NCOUT) {
    const int ch = tid;
    const int f = ch & 15, j = ch >> 4;
    float s = 0.f, s2 = 0.f;
#pragma unroll
    for (int w = 0; w < 4; ++w) {
      s  += redS[w * 128 + f * 8 + j];
      s2 += redQ[w * 128 + f * 8 + j];
    }
    atomicAdd(&sum2[ch], s);
    atomicAdd(&sq2[ch], s2);
  }
}

// ---------------- final: BN2-affine + ReLU, bf16 h2 -> fp32 out ----------------
__global__ __launch_bounds__(256) void final_kernel(
    const unsigned short* __restrict__ h2bf, float* __restrict__ out,
    const float* __restrict__ a2, const float* __restrict__ d2)
{
  __shared__ float sa[NCOUT], sd[NCOUT];
  if (threadIdx.x < NCOUT) { sa[threadIdx.x] = a2[threadIdx.x]; sd[threadIdx.x] = d2[threadIdx.x]; }
  __syncthreads();
  const int total8 = BNTOT * NCOUT / 8;
  for (int i = blockIdx.x * blockDim.x + threadIdx.x; i < total8;
       i += gridDim.x * blockDim.x) {
    PK8 v; v.q = ((const uint4*)h2bf)[i];
    const int c = (i & 15) * 8;
    float4 o0, o1;
    o0.x = fmaxf(0.f, sa[c + 0] * bf2f(v.u[0]) + sd[c + 0]);
    o0.y = fmaxf(0.f, sa[c + 1] * bf2f(v.u[1]) + sd[c + 1]);
    o0.z = fmaxf(0.f, sa[c + 2] * bf2f(v.u[2]) + sd[c + 2]);
    o0.w = fmaxf(0.f, sa[c + 3] * bf2f(v.u[3]) + sd[c + 3]);
    o1.x = fmaxf(0.f, sa[c + 4] * bf2f(v.u[4]) + sd[c + 4]);
    o1.y = fmaxf(0.f, sa[c + 5] * bf2f(v.u[5]) + sd[c + 5]);
    o1.z = fmaxf(0.f, sa[c + 6] * bf2f(v.u[6]) + sd[c + 6]);
    o1.w = fmaxf(0.f, sa[c + 7] * bf2f(v.u[7]) + sd[c + 7]);
    ((float4*)out)[i * 2]     = o0;
    ((float4*)out)[i * 2 + 1] = o1;
  }
}

extern "C" void kernel_launch(void* const* d_in, const int* in_sizes, int n_in,
                              void* d_out, int out_size, void* d_ws, size_t ws_size,
                              hipStream_t stream) {
  const float* xyz1    = (const float*)d_in[0];
  const float* xyz2    = (const float*)d_in[1];
  const float* points1 = (const float*)d_in[2];
  const float* points2 = (const float*)d_in[3];
  const float* W1      = (const float*)d_in[4];
  const float* b1      = (const float*)d_in[5];
  const float* g1      = (const float*)d_in[6];
  const float* be1     = (const float*)d_in[7];
  const float* W2      = (const float*)d_in[8];
  const float* b2      = (const float*)d_in[9];
  const float* g2      = (const float*)d_in[10];
  const float* be2     = (const float*)d_in[11];
  float* out = (float*)d_out;

  char* ws = (char*)d_ws;
  const size_t h1_bytes  = (size_t)BNTOT * NCMID * 2;    // 32 MB
  const size_t h2_bytes  = (size_t)BNTOT * NCOUT * 2;    // 16 MB
  const size_t w1b_bytes = (size_t)NCMID * NCIN * 2;     // 192 KB
  const size_t w2b_bytes = (size_t)NCOUT * NCMID * 2;    // 64 KB
  const size_t ps_bytes  = (size_t)1024 * NCMID * 4;     // 1 MB
  unsigned short* h1bf = (unsigned short*)ws;
  unsigned short* h2bf = (unsigned short*)(ws + h1_bytes);
  unsigned short* W1bf = (unsigned short*)(ws + h1_bytes + h2_bytes);
  unsigned short* W2bf = (unsigned short*)(ws + h1_bytes + h2_bytes + w1b_bytes);
  float* pS = (float*)(ws + h1_bytes + h2_bytes + w1b_bytes + w2b_bytes);
  float* pQ = (float*)(ws + h1_bytes + h2_bytes + w1b_bytes + w2b_bytes + ps_bytes);
  float* stats = (float*)(ws + h1_bytes + h2_bytes + w1b_bytes + w2b_bytes + 2 * ps_bytes);
  float* sum1 = stats;
  float* sq1  = stats + 256;
  float* sum2 = stats + 512;
  float* sq2  = stats + 640;
  float* a1   = stats + 768;
  float* dd1  = stats + 1024;
  float* a2v  = stats + 1280;
  float* dd2v = stats + 1408;

  hipMemsetAsync(stats, 0, 768 * sizeof(float), stream);

  prep_w_kernel<<<128, 256, 0, stream>>>(W1, W2, W1bf, W2bf);
  fg1_kernel<<<BNTOT / 64, 256, 0, stream>>>(xyz1, xyz2, points1, points2,
                                             W1bf, b1, h1bf, pS, pQ);
  colred_kernel<<<32, 256, 0, stream>>>(pS, pQ, sum1, sq1);
  stats_kernel<NCMID><<<1, NCMID, 0, stream>>>(sum1, sq1, g1, be1, a1, dd1);
  gemm2_kernel<<<BNTOT / 128, 256, 0, stream>>>(h1bf, W2bf, b2, a1, dd1, h2bf, sum2, sq2);
  stats_kernel<NCOUT><<<1, NCOUT, 0, stream>>>(sum2, sq2, g2, be2, a2v, dd2v);
  final_kernel<<<2048, 256, 0, stream>>>(h2bf, out, a2v, dd2v);
}

// Round 8
// 177.059 us; speedup vs baseline: 1.2121x; 1.2121x over previous
//
#include <hip/hip_runtime.h>
#include <hip/hip_bf16.h>

#define NB    16
#define NPT   4096
#define NSRC  1024
#define ND1   128
#define ND2   256
#define NCIN  384
#define NCMID 256
#define NCOUT 128
#define BNTOT (NB * NPT)   // 65536 points
#define BN_EPS 1e-5f

typedef float f32x4 __attribute__((ext_vector_type(4)));
typedef short bf16x8 __attribute__((ext_vector_type(8)));
typedef unsigned int uint;

union PK8 { unsigned short u[8]; uint4 q; };
union PK4 { unsigned short u[4]; uint2 q; };

static __device__ __forceinline__ unsigned short f2bf(float f) {
  __hip_bfloat16 h = __float2bfloat16(f);
  return __builtin_bit_cast(unsigned short, h);
}
static __device__ __forceinline__ float bf2f(unsigned short u) {
  return __builtin_bit_cast(float, (uint)u << 16);
}
static __device__ __forceinline__ void gl_lds16(const unsigned short* g, unsigned short* l) {
  __builtin_amdgcn_global_load_lds(
      (const __attribute__((address_space(1))) uint*)(const void*)g,
      (__attribute__((address_space(3))) uint*)(void*)l,
      16, 0, 0);
}

#if __has_builtin(__builtin_amdgcn_fmed3f)
#define MED3F(a, b, c) __builtin_amdgcn_fmed3f((a), (b), (c))
#else
#define MED3F(a, b, c) fmaxf((a), fminf((b), (c)))
#endif

// total order: (d, idx) with ties -> lower index (matches lax.top_k)
static __device__ __forceinline__ bool prec(float da, int ia, float db, int ib) {
  return (da < db) || (da == db && ia < ib);
}

// shallow branchless top-3 insert (proven rounds 5/6)
#define INSV(t0, t1, t2, j0, j1, j2, d, idx)                                   \
  {                                                                            \
    const bool c0 = (d) < t0;                                                  \
    const bool c1 = (d) < t1;                                                  \
    const bool c2 = (d) < t2;                                                  \
    const float m1 = MED3F(t0, t1, (d));                                       \
    const float m2 = fminf(t2, fmaxf(t1, (d)));                                \
    t0 = fminf(t0, (d));                                                       \
    j2 = c2 ? (c1 ? j1 : (idx)) : j2;                                          \
    j1 = c1 ? (c0 ? j0 : (idx)) : j1;                                          \
    j0 = c0 ? (idx) : j0;                                                      \
    t1 = m1; t2 = m2;                                                          \
  }

#define MERGE3(d0, j0, d1, j1, d2, j2, e0, i0, e1, i1, e2, i2)                 \
  {                                                                            \
    const bool p0 = prec(d0, j0, e0, i0);                                      \
    const float l0d = p0 ? e0 : d0; const int l0j = p0 ? i0 : j0;              \
    const float r0d = p0 ? d0 : e0; const int r0j = p0 ? j0 : i0;              \
    const bool p1 = prec(d1, j1, e1, i1);                                      \
    const float w1d = p1 ? d1 : e1; const int w1j = p1 ? j1 : i1;              \
    const bool pr1 = prec(l0d, l0j, w1d, w1j);                                 \
    const float r1d = pr1 ? l0d : w1d; const int r1j = pr1 ? l0j : w1j;        \
    const float q1d = pr1 ? w1d : l0d; const int q1j = pr1 ? w1j : l0j;        \
    const bool p2 = prec(d2, j2, e2, i2);                                      \
    const float w2d = p2 ? d2 : e2; const int w2j = p2 ? j2 : i2;              \
    const bool pr2 = prec(q1d, q1j, w2d, w2j);                                 \
    const float r2d = pr2 ? q1d : w2d; const int r2j = pr2 ? q1j : w2j;        \
    d0 = r0d; j0 = r0j; d1 = r1d; j1 = r1j; d2 = r2d; j2 = r2j;                \
  }

// one kNN pair step on the shared state (candidates i and i+1)
#define KNN_PAIR(i)                                                            \
  {                                                                            \
    const float4 va = n_slab[(i)];                                             \
    float da = va.w + n_a2;                                                    \
    da = fmaf(va.x, n_ax, da); da = fmaf(va.y, n_ay, da); da = fmaf(va.z, n_az, da); \
    INSV(n_ta0, n_ta1, n_ta2, n_ja0, n_ja1, n_ja2, da, n_qbase + (i));         \
    const float4 vb = n_slab[(i) + 1];                                         \
    float db = vb.w + n_a2;                                                    \
    db = fmaf(vb.x, n_ax, db); db = fmaf(vb.y, n_ay, db); db = fmaf(vb.z, n_az, db); \
    INSV(n_tb0, n_tb1, n_tb2, n_jb0, n_jb1, n_jb2, db, n_qbase + (i) + 1);     \
  }

// ---------------- prep: W1,W2 fp32 -> bf16 ----------------
__global__ __launch_bounds__(256) void prep_w_kernel(
    const float* __restrict__ w1, const float* __restrict__ w2,
    unsigned short* __restrict__ w1b, unsigned short* __restrict__ w2b)
{
  const int i = blockIdx.x * 256 + threadIdx.x;
  const bool isW1 = i < 24576;
  const float4 v = isW1 ? ((const float4*)w1)[i] : ((const float4*)w2)[i - 24576];
  PK4 pk;
  pk.u[0] = f2bf(v.x); pk.u[1] = f2bf(v.y); pk.u[2] = f2bf(v.z); pk.u[3] = f2bf(v.w);
  if (isW1) ((uint2*)w1b)[i] = pk.q;
  else      ((uint2*)w2b)[i - 24576] = pk.q;
}

// ============ fg1 v4: chunk-pipelined kNN + interp + GEMM1 + BN1 partials ============
// 512 blocks x 256 thr (4 waves). Block handles 2 chunks of 64 pts (same batch).
// Pipeline: knn(c0) -> ktloop(c0) interleaving knn(c1) slices -> ktloop(c1).
// B via global_load_lds dbuf (r5/r6 proven); A reg-staged T14 (issue early, ds_write late).
__global__ __launch_bounds__(256, 2) void fg1_kernel(
    const float* __restrict__ xyz1, const float* __restrict__ xyz2,
    const float* __restrict__ points1, const float* __restrict__ points2,
    const unsigned short* __restrict__ W1bf, const float* __restrict__ bias1,
    unsigned short* __restrict__ h1bf, float* __restrict__ pS, float* __restrict__ pQ)
{
  __shared__ unsigned short sA[2][64][32];    // 8 KB
  __shared__ unsigned short sB[2][256][32];   // 32 KB
  __shared__ float4 s2t[4 * 257];             // 16.45 KB
  __shared__ float redS[4][256];              // 4 KB
  __shared__ float redQ[4][256];              // 4 KB   (total ~64.5 KB -> 2 blk/CU)

  const int tid = threadIdx.x;
  const int lane = tid & 63;
  const int wave = tid >> 6;

  // XCD-aware bijective mapping: XCD x owns batches 2x, 2x+1 (points2 slab -> own L2)
  const int w = blockIdx.x;                   // 512 blocks
  const int xcd = w & 7, rr = w >> 3;
  const int batch = 2 * xcd + (rr & 1);
  const int ptBase0 = batch * NPT + (rr >> 1) * 128;   // chunk c at ptBase0 + c*64

  const int fr = lane & 15;
  const int cs = lane >> 4;
  const int rdsh = ((cs ^ ((fr >> 1) & 3)) << 3);

  // A-slot decomposition (thread = slot): row 0..63, swizzled k-segment
  const int arow = tid >> 2;
  const int aks = (tid & 3) ^ ((arow >> 1) & 3);

  auto stageB = [&](int buf, int kt) {
    const int k0 = kt * 32;
#pragma unroll
    for (int c = 0; c < 4; ++c) {
      const int base = c * 256 + wave * 64;   // wave-uniform LDS chunk base
      const int s = base + lane;
      const int row = s >> 2, c16 = s & 3;
      const int ks = c16 ^ ((row >> 1) & 3);
      gl_lds16(W1bf + (size_t)row * NCIN + k0 + ks * 8, &sB[buf][0][0] + base * 8);
    }
  };

  // T14 issue: global loads for A fragment (kt) into regs
  auto issueA = [&](float4* v, int c, int kt,
                    const float* r0p, const float* r1p, const float* r2p) {
    const int k = kt * 32 + aks * 8;
    if (kt < 4) {
      const float* src = points1 + (size_t)(ptBase0 + c * 64 + arow) * ND1 + k;
      v[0] = ((const float4*)src)[0];
      v[1] = ((const float4*)src)[1];
    } else {
      const int ko = k - ND1;
      v[0] = *(const float4*)(r0p + ko); v[1] = *(const float4*)(r0p + ko + 4);
      v[2] = *(const float4*)(r1p + ko); v[3] = *(const float4*)(r1p + ko + 4);
      v[4] = *(const float4*)(r2p + ko); v[5] = *(const float4*)(r2p + ko + 4);
    }
  };
  // T14 write: convert (+3NN combine) and ds_write to linear slot
  auto writeA = [&](int buf, int kt, const float4* v, float w0, float w1, float w2) {
    PK8 pk;
    if (kt < 4) {
      pk.u[0] = f2bf(v[0].x); pk.u[1] = f2bf(v[0].y); pk.u[2] = f2bf(v[0].z); pk.u[3] = f2bf(v[0].w);
      pk.u[4] = f2bf(v[1].x); pk.u[5] = f2bf(v[1].y); pk.u[6] = f2bf(v[1].z); pk.u[7] = f2bf(v[1].w);
    } else {
#pragma unroll
      for (int h = 0; h < 2; ++h) {
        const float4 va = v[h], vb = v[2 + h], vc = v[4 + h];
        pk.u[h * 4 + 0] = f2bf(w0 * va.x + w1 * vb.x + w2 * vc.x);
        pk.u[h * 4 + 1] = f2bf(w0 * va.y + w1 * vb.y + w2 * vc.y);
        pk.u[h * 4 + 2] = f2bf(w0 * va.z + w1 * vb.z + w2 * vc.z);
        pk.u[h * 4 + 3] = f2bf(w0 * va.w + w1 * vb.w + w2 * vc.w);
      }
    }
    *(uint4*)(&sA[buf][0][0] + tid * 8) = pk.q;
  };

  // ---- kNN state (register-resident; reused for both chunks) ----
  float n_ta0, n_ta1, n_ta2, n_tb0, n_tb1, n_tb2;
  int   n_ja0, n_ja1, n_ja2, n_jb0, n_jb1, n_jb2;
  float n_ax, n_ay, n_az, n_a2;
  const float4* n_slab = &s2t[(tid & 3) * 257];
  const int n_qbase = (tid & 3) * 256;

  auto knnInit = [&](int p) {
    n_ax = xyz1[(size_t)p * 3 + 0];
    n_ay = xyz1[(size_t)p * 3 + 1];
    n_az = xyz1[(size_t)p * 3 + 2];
    n_a2 = n_ax * n_ax + n_ay * n_ay + n_az * n_az;
    n_ta0 = n_ta1 = n_ta2 = n_tb0 = n_tb1 = n_tb2 = 3.4e38f;
    n_ja0 = n_ja1 = n_ja2 = n_jb0 = n_jb1 = n_jb2 = 0;
  };
  const float* p2base = points2 + (size_t)batch * NSRC * ND2;
  auto knnFinish = [&](const float*& o0, const float*& o1, const float*& o2,
                       float& w0o, float& w1o, float& w2o) {
    MERGE3(n_ta0, n_ja0, n_ta1, n_ja1, n_ta2, n_ja2,
           n_tb0, n_jb0, n_tb1, n_jb1, n_tb2, n_jb2);
#pragma unroll
    for (int m = 1; m <= 2; m <<= 1) {
      float e0 = __shfl_xor(n_ta0, m), e1 = __shfl_xor(n_ta1, m), e2 = __shfl_xor(n_ta2, m);
      int i0 = __shfl_xor(n_ja0, m), i1 = __shfl_xor(n_ja1, m), i2 = __shfl_xor(n_ja2, m);
      MERGE3(n_ta0, n_ja0, n_ta1, n_ja1, n_ta2, n_ja2, e0, i0, e1, i1, e2, i2);
    }
    float w0 = 1.f / (n_ta0 + 1e-8f), w1 = 1.f / (n_ta1 + 1e-8f), w2 = 1.f / (n_ta2 + 1e-8f);
    const float inv = 1.f / (w0 + w1 + w2);
    w0o = w0 * inv; w1o = w1 * inv; w2o = w2 * inv;
    o0 = p2base + (size_t)n_ja0 * ND2;
    o1 = p2base + (size_t)n_ja1 * ND2;
    o2 = p2base + (size_t)n_ja2 * ND2;
  };

  f32x4 acc[16];
#pragma unroll
  for (int j = 0; j < 16; ++j)
#pragma unroll
    for (int q = 0; q < 4; ++q) acc[j][q] = 0.0f;

  auto epilogue = [&](int c) {
    const int r0 = cs * 4;
#pragma unroll
    for (int j = 0; j < 16; ++j) {
      const int ch = j * 16 + fr;
      const float bb = bias1[ch];
      float s = 0.f, s2 = 0.f;
#pragma unroll
      for (int q = 0; q < 4; ++q) {
        const int pt = ptBase0 + c * 64 + wave * 16 + r0 + q;
        const float v = acc[j][q] + bb;
        h1bf[(size_t)pt * NCMID + ch] = f2bf(v);
        s += v; s2 += v * v;
      }
      s += __shfl_xor(s, 16);  s2 += __shfl_xor(s2, 16);
      s += __shfl_xor(s, 32);  s2 += __shfl_xor(s2, 32);
      if (cs == 0) { redS[wave][ch] = s; redQ[wave][ch] = s2; }
    }
    __syncthreads();
    {
      const int ch = tid;
      const float s  = redS[0][ch] + redS[1][ch] + redS[2][ch] + redS[3][ch];
      const float s2 = redQ[0][ch] + redQ[1][ch] + redQ[2][ch] + redQ[3][ch];
      pS[(size_t)(blockIdx.x * 2 + c) * NCMID + ch] = s;
      pQ[(size_t)(blockIdx.x * 2 + c) * NCMID + ch] = s2;
    }
#pragma unroll
    for (int j = 0; j < 16; ++j)
#pragma unroll
      for (int q = 0; q < 4; ++q) acc[j][q] = 0.0f;
  };

  // ================= prologue =================
  float4 vst[6];
  stageB(0, 0);
  issueA(vst, 0, 0, nullptr, nullptr, nullptr);        // chunk0 kt0 = points1
  { // stage + transform xyz2 (proven r5/r7 code)
    const float* src = xyz2 + (size_t)batch * NSRC * 3 + tid * 12;
    const float4 l0 = ((const float4*)src)[0];
    const float4 l1 = ((const float4*)src)[1];
    const float4 l2 = ((const float4*)src)[2];
    const float xs[4] = {l0.x, l0.w, l1.z, l2.y};
    const float ys[4] = {l0.y, l1.x, l1.w, l2.z};
    const float zs[4] = {l0.z, l1.y, l2.x, l2.w};
    const int qq = tid >> 6;
    const int ibase = (tid & 63) * 4;
#pragma unroll
    for (int u = 0; u < 4; ++u) {
      const float c = xs[u] * xs[u] + ys[u] * ys[u] + zs[u] * zs[u];
      float4 v;
      v.x = -2.0f * xs[u]; v.y = -2.0f * ys[u]; v.z = -2.0f * zs[u]; v.w = c;
      s2t[qq * 257 + ibase + u] = v;
    }
  }
  writeA(0, 0, vst, 0.f, 0.f, 0.f);
  __syncthreads();    // s2t + sA[0] + sB[0] (vmcnt drained) visible

  // ---- kNN chunk 0 (full scan) ----
  knnInit(ptBase0 + (tid >> 2));
  for (int i2 = 0; i2 < 128; ++i2) KNN_PAIR(2 * i2);
  const float *c0r0, *c0r1, *c0r2; float c0w0, c0w1, c0w2;
  knnFinish(c0r0, c0r1, c0r2, c0w0, c0w1, c0w2);

  // ---- init kNN chunk 1 (sliced through chunk0's kt loop) ----
  knnInit(ptBase0 + 64 + (tid >> 2));
  int ki = 0;

  int buf = 0;
  // ================= chunk 0 K-loop (with knn(c1) filler) =================
  for (int kt = 0; kt < 12; ++kt) {
    if (kt < 11) { stageB(buf ^ 1, kt + 1); issueA(vst, 0, kt + 1, c0r0, c0r1, c0r2); }
    else         { stageB(buf ^ 1, 0);      issueA(vst, 1, 0, nullptr, nullptr, nullptr); }
    for (int u = 0; u < 11 && ki < 128; ++u, ++ki) KNN_PAIR(2 * ki);
    const bf16x8 a = *(const bf16x8*)&sA[buf][wave * 16 + fr][rdsh];
#pragma unroll
    for (int j = 0; j < 16; ++j) {
      const bf16x8 bv = *(const bf16x8*)&sB[buf][j * 16 + fr][rdsh];
      acc[j] = __builtin_amdgcn_mfma_f32_16x16x32_bf16(a, bv, acc[j], 0, 0, 0);
    }
    writeA(buf ^ 1, (kt < 11) ? kt + 1 : 0, vst, c0w0, c0w1, c0w2);
    __syncthreads();
    buf ^= 1;
  }
  epilogue(0);

  // ---- finish kNN chunk 1 ----
  const float *c1r0, *c1r1, *c1r2; float c1w0, c1w1, c1w2;
  knnFinish(c1r0, c1r1, c1r2, c1w0, c1w1, c1w2);

  // ================= chunk 1 K-loop =================
  for (int kt = 0; kt < 12; ++kt) {
    if (kt < 11) { stageB(buf ^ 1, kt + 1); issueA(vst, 1, kt + 1, c1r0, c1r1, c1r2); }
    const bf16x8 a = *(const bf16x8*)&sA[buf][wave * 16 + fr][rdsh];
#pragma unroll
    for (int j = 0; j < 16; ++j) {
      const bf16x8 bv = *(const bf16x8*)&sB[buf][j * 16 + fr][rdsh];
      acc[j] = __builtin_amdgcn_mfma_f32_16x16x32_bf16(a, bv, acc[j], 0, 0, 0);
    }
    if (kt < 11) writeA(buf ^ 1, kt + 1, vst, c1w0, c1w1, c1w2);
    __syncthreads();
    buf ^= 1;
  }
  epilogue(1);
}

// ---------------- reduce per-chunk BN1 partials (1024 rows) ----------------
__global__ __launch_bounds__(256) void colred_kernel(
    const float* __restrict__ pS, const float* __restrict__ pQ,
    float* __restrict__ sum1, float* __restrict__ sq1)
{
  const int ch = threadIdx.x;
  const int r0 = blockIdx.x * 32;             // 32 blocks x 32 rows
  float s = 0.f, s2 = 0.f;
  for (int i = 0; i < 32; ++i) {
    s  += pS[(size_t)(r0 + i) * NCMID + ch];
    s2 += pQ[(size_t)(r0 + i) * NCMID + ch];
  }
  atomicAdd(&sum1[ch], s);
  atomicAdd(&sq1[ch], s2);
}

// ---------------- fold BN into per-channel affine: y = a*x + d ----------------
template <int C>
__global__ void stats_kernel(const float* __restrict__ sum, const float* __restrict__ sumsq,
                             const float* __restrict__ g, const float* __restrict__ be,
                             float* __restrict__ a, float* __restrict__ d)
{
  const int c = threadIdx.x;
  const float mean = sum[c] * (1.0f / BNTOT);
  const float var = sumsq[c] * (1.0f / BNTOT) - mean * mean;
  const float inv = rsqrtf(var + BN_EPS);
  const float ac = g[c] * inv;
  a[c] = ac;
  d[c] = be[c] - mean * ac;
}

// ---------------- GEMM2 (+fused BN2 column sums, bf16 out) — proven r5-r7 ----------------
__global__ __launch_bounds__(256, 2) void gemm2_kernel(
    const unsigned short* __restrict__ h1bf, const unsigned short* __restrict__ W2bf,
    const float* __restrict__ bias2, const float* __restrict__ aff_a,
    const float* __restrict__ aff_d, unsigned short* __restrict__ h2bf,
    float* __restrict__ sum2, float* __restrict__ sq2)
{
  __shared__ unsigned short sA[2][128][32];
  __shared__ unsigned short sB[2][128][32];
  __shared__ float sa[NCMID], sd[NCMID];
  const int tid = threadIdx.x;
  const int lane = tid & 63;
  const int wave = tid >> 6;
  const int ptBase = blockIdx.x * 128;
  sa[tid] = aff_a[tid];
  sd[tid] = aff_d[tid];

  f32x4 acc[2][8];
#pragma unroll
  for (int m = 0; m < 2; ++m)
#pragma unroll
    for (int j = 0; j < 8; ++j)
#pragma unroll
      for (int q = 0; q < 4; ++q) acc[m][j][q] = 0.0f;

  const int fr = lane & 15;
  const int cs = lane >> 4;
  const int rdsh = ((cs ^ ((fr >> 1) & 3)) << 3);

  auto stageB = [&](int buf, int kt) {
    const int k0 = kt * 32;
#pragma unroll
    for (int c = 0; c < 2; ++c) {
      const int s = c * 256 + wave * 64 + lane;
      const int row = s >> 2, c16 = s & 3;
      const int ks = c16 ^ ((row >> 1) & 3);
      gl_lds16(W2bf + (size_t)row * NCMID + k0 + ks * 8,
               &sB[buf][0][0] + (c * 256 + wave * 64) * 8);
    }
  };
  auto stageA = [&](int buf, int kt) {
    const int k0 = kt * 32;
#pragma unroll
    for (int c = 0; c < 2; ++c) {
      const int s = c * 256 + tid;
      const int row = s >> 2, c16 = s & 3;
      const int ks = c16 ^ ((row >> 1) & 3);
      const int k = k0 + ks * 8;
      PK8 v;
      v.q = *(const uint4*)(h1bf + (size_t)(ptBase + row) * NCMID + k);
      PK8 pk;
#pragma unroll
      for (int j = 0; j < 8; ++j)
        pk.u[j] = f2bf(fmaxf(0.f, sa[k + j] * bf2f(v.u[j]) + sd[k + j]));
      *(uint4*)(&sA[buf][0][0] + s * 8) = pk.q;
    }
  };

  stageB(0, 0);
  __syncthreads();
  stageA(0, 0);
  __syncthreads();
  int cur = 0;
  for (int kt = 0; kt < 8; ++kt) {
    if (kt < 7) { stageB(cur ^ 1, kt + 1); stageA(cur ^ 1, kt + 1); }
    const bf16x8 a0 = *(const bf16x8*)&sA[cur][wave * 32 + fr][rdsh];
    const bf16x8 a1 = *(const bf16x8*)&sA[cur][wave * 32 + 16 + fr][rdsh];
#pragma unroll
    for (int j = 0; j < 8; ++j) {
      const bf16x8 b = *(const bf16x8*)&sB[cur][j * 16 + fr][rdsh];
      acc[0][j] = __builtin_amdgcn_mfma_f32_16x16x32_bf16(a0, b, acc[0][j], 0, 0, 0);
      acc[1][j] = __builtin_amdgcn_mfma_f32_16x16x32_bf16(a1, b, acc[1][j], 0, 0, 0);
    }
    __syncthreads();
    cur ^= 1;
  }

  float* redS = (float*)&sA[0][0][0];
  float* redQ = redS + 512;
  const int col = fr;
  const int r0 = cs * 4;
#pragma unroll
  for (int j = 0; j < 8; ++j) {
    const int ch = j * 16 + col;
    const float bb = bias2[ch];
    float s = 0.f, s2 = 0.f;
#pragma unroll
    for (int m = 0; m < 2; ++m)
#pragma unroll
      for (int q = 0; q < 4; ++q) {
        const int pt = ptBase + wave * 32 + m * 16 + r0 + q;
        const float v = acc[m][j][q] + bb;
        h2bf[(size_t)pt * NCOUT + ch] = f2bf(v);
        s += v; s2 += v * v;
      }
    s += __shfl_xor(s, 16);  s2 += __shfl_xor(s2, 16);
    s += __shfl_xor(s, 32);  s2 += __shfl_xor(s2, 32);
    if (cs == 0) { redS[wave * 128 + fr * 8 + j] = s; redQ[wave * 128 + fr * 8 + j] = s2; }
  }
  __syncthreads();
  if (tid < NCOUT) {
    const int ch = tid;
    const int f = ch & 15, j = ch >> 4;
    float s = 0.f, s2 = 0.f;
#pragma unroll
    for (int w = 0; w < 4; ++w) {
      s  += redS[w * 128 + f * 8 + j];
      s2 += redQ[w * 128 + f * 8 + j];
    }
    atomicAdd(&sum2[ch], s);
    atomicAdd(&sq2[ch], s2);
  }
}

// ---------------- final: BN2-affine + ReLU, bf16 h2 -> fp32 out ----------------
__global__ __launch_bounds__(256) void final_kernel(
    const unsigned short* __restrict__ h2bf, float* __restrict__ out,
    const float* __restrict__ a2, const float* __restrict__ d2)
{
  __shared__ float sa[NCOUT], sd[NCOUT];
  if (threadIdx.x < NCOUT) { sa[threadIdx.x] = a2[threadIdx.x]; sd[threadIdx.x] = d2[threadIdx.x]; }
  __syncthreads();
  const int total8 = BNTOT * NCOUT / 8;
  for (int i = blockIdx.x * blockDim.x + threadIdx.x; i < total8;
       i += gridDim.x * blockDim.x) {
    PK8 v; v.q = ((const uint4*)h2bf)[i];
    const int c = (i & 15) * 8;
    float4 o0, o1;
    o0.x = fmaxf(0.f, sa[c + 0] * bf2f(v.u[0]) + sd[c + 0]);
    o0.y = fmaxf(0.f, sa[c + 1] * bf2f(v.u[1]) + sd[c + 1]);
    o0.z = fmaxf(0.f, sa[c + 2] * bf2f(v.u[2]) + sd[c + 2]);
    o0.w = fmaxf(0.f, sa[c + 3] * bf2f(v.u[3]) + sd[c + 3]);
    o1.x = fmaxf(0.f, sa[c + 4] * bf2f(v.u[4]) + sd[c + 4]);
    o1.y = fmaxf(0.f, sa[c + 5] * bf2f(v.u[5]) + sd[c + 5]);
    o1.z = fmaxf(0.f, sa[c + 6] * bf2f(v.u[6]) + sd[c + 6]);
    o1.w = fmaxf(0.f, sa[c + 7] * bf2f(v.u[7]) + sd[c + 7]);
    ((float4*)out)[i * 2]     = o0;
    ((float4*)out)[i * 2 + 1] = o1;
  }
}

extern "C" void kernel_launch(void* const* d_in, const int* in_sizes, int n_in,
                              void* d_out, int out_size, void* d_ws, size_t ws_size,
                              hipStream_t stream) {
  const float* xyz1    = (const float*)d_in[0];
  const float* xyz2    = (const float*)d_in[1];
  const float* points1 = (const float*)d_in[2];
  const float* points2 = (const float*)d_in[3];
  const float* W1      = (const float*)d_in[4];
  const float* b1      = (const float*)d_in[5];
  const float* g1      = (const float*)d_in[6];
  const float* be1     = (const float*)d_in[7];
  const float* W2      = (const float*)d_in[8];
  const float* b2      = (const float*)d_in[9];
  const float* g2      = (const float*)d_in[10];
  const float* be2     = (const float*)d_in[11];
  float* out = (float*)d_out;

  char* ws = (char*)d_ws;
  const size_t h1_bytes  = (size_t)BNTOT * NCMID * 2;    // 32 MB
  const size_t h2_bytes  = (size_t)BNTOT * NCOUT * 2;    // 16 MB
  const size_t w1b_bytes = (size_t)NCMID * NCIN * 2;     // 192 KB
  const size_t w2b_bytes = (size_t)NCOUT * NCMID * 2;    // 64 KB
  const size_t ps_bytes  = (size_t)1024 * NCMID * 4;     // 1 MB
  unsigned short* h1bf = (unsigned short*)ws;
  unsigned short* h2bf = (unsigned short*)(ws + h1_bytes);
  unsigned short* W1bf = (unsigned short*)(ws + h1_bytes + h2_bytes);
  unsigned short* W2bf = (unsigned short*)(ws + h1_bytes + h2_bytes + w1b_bytes);
  float* pS = (float*)(ws + h1_bytes + h2_bytes + w1b_bytes + w2b_bytes);
  float* pQ = (float*)(ws + h1_bytes + h2_bytes + w1b_bytes + w2b_bytes + ps_bytes);
  float* stats = (float*)(ws + h1_bytes + h2_bytes + w1b_bytes + w2b_bytes + 2 * ps_bytes);
  float* sum1 = stats;
  float* sq1  = stats + 256;
  float* sum2 = stats + 512;
  float* sq2  = stats + 640;
  float* a1   = stats + 768;
  float* dd1  = stats + 1024;
  float* a2v  = stats + 1280;
  float* dd2v = stats + 1408;

  hipMemsetAsync(stats, 0, 768 * sizeof(float), stream);

  prep_w_kernel<<<128, 256, 0, stream>>>(W1, W2, W1bf, W2bf);
  fg1_kernel<<<512, 256, 0, stream>>>(xyz1, xyz2, points1, points2,
                                      W1bf, b1, h1bf, pS, pQ);
  colred_kernel<<<32, 256, 0, stream>>>(pS, pQ, sum1, sq1);
  stats_kernel<NCMID><<<1, NCMID, 0, stream>>>(sum1, sq1, g1, be1, a1, dd1);
  gemm2_kernel<<<BNTOT / 128, 256, 0, stream>>>(h1bf, W2bf, b2, a1, dd1, h2bf, sum2, sq2);
  stats_kernel<NCOUT><<<1, NCOUT, 0, stream>>>(sum2, sq2, g2, be2, a2v, dd2v);
  final_kernel<<<2048, 256, 0, stream>>>(h2bf, out, a2v, dd2v);
}

// Round 9
// 130.550 us; speedup vs baseline: 1.6440x; 1.3563x over previous
//
#include <hip/hip_runtime.h>
#include <hip/hip_bf16.h>

#define NB    16
#define NPT   4096
#define NSRC  1024
#define ND1   128
#define ND2   256
#define NCIN  384
#define NCMID 256
#define NCOUT 128
#define BNTOT (NB * NPT)   // 65536 points
#define BN_EPS 1e-5f

typedef float f32x4 __attribute__((ext_vector_type(4)));
typedef short bf16x8 __attribute__((ext_vector_type(8)));
typedef unsigned int uint;

union PK8 { unsigned short u[8]; uint4 q; };
union PK4 { unsigned short u[4]; uint2 q; };

static __device__ __forceinline__ unsigned short f2bf(float f) {
  __hip_bfloat16 h = __float2bfloat16(f);
  return __builtin_bit_cast(unsigned short, h);
}
static __device__ __forceinline__ float bf2f(unsigned short u) {
  return __builtin_bit_cast(float, (uint)u << 16);
}
static __device__ __forceinline__ void gl_lds16(const unsigned short* g, unsigned short* l) {
  __builtin_amdgcn_global_load_lds(
      (const __attribute__((address_space(1))) uint*)(const void*)g,
      (__attribute__((address_space(3))) uint*)(void*)l,
      16, 0, 0);
}

#if __has_builtin(__builtin_amdgcn_fmed3f)
#define MED3F(a, b, c) __builtin_amdgcn_fmed3f((a), (b), (c))
#else
#define MED3F(a, b, c) fmaxf((a), fminf((b), (c)))
#endif

// total order: (d, idx) with ties -> lower index (matches lax.top_k)
static __device__ __forceinline__ bool prec(float da, int ia, float db, int ib) {
  return (da < db) || (da == db && ia < ib);
}

// shallow branchless top-3 insert (proven rounds 5/6)
#define INSV(t0, t1, t2, j0, j1, j2, d, idx)                                   \
  {                                                                            \
    const bool c0 = (d) < t0;                                                  \
    const bool c1 = (d) < t1;                                                  \
    const bool c2 = (d) < t2;                                                  \
    const float m1 = MED3F(t0, t1, (d));                                       \
    const float m2 = fminf(t2, fmaxf(t1, (d)));                                \
    t0 = fminf(t0, (d));                                                       \
    j2 = c2 ? (c1 ? j1 : (idx)) : j2;                                          \
    j1 = c1 ? (c0 ? j0 : (idx)) : j1;                                          \
    j0 = c0 ? (idx) : j0;                                                      \
    t1 = m1; t2 = m2;                                                          \
  }

#define MERGE3(d0, j0, d1, j1, d2, j2, e0, i0, e1, i1, e2, i2)                 \
  {                                                                            \
    const bool p0 = prec(d0, j0, e0, i0);                                      \
    const float l0d = p0 ? e0 : d0; const int l0j = p0 ? i0 : j0;              \
    const float r0d = p0 ? d0 : e0; const int r0j = p0 ? j0 : i0;              \
    const bool p1 = prec(d1, j1, e1, i1);                                      \
    const float w1d = p1 ? d1 : e1; const int w1j = p1 ? j1 : i1;              \
    const bool pr1 = prec(l0d, l0j, w1d, w1j);                                 \
    const float r1d = pr1 ? l0d : w1d; const int r1j = pr1 ? l0j : w1j;        \
    const float q1d = pr1 ? w1d : l0d; const int q1j = pr1 ? w1j : l0j;        \
    const bool p2 = prec(d2, j2, e2, i2);                                      \
    const float w2d = p2 ? d2 : e2; const int w2j = p2 ? j2 : i2;              \
    const bool pr2 = prec(q1d, q1j, w2d, w2j);                                 \
    const float r2d = pr2 ? q1d : w2d; const int r2j = pr2 ? q1j : w2j;        \
    d0 = r0d; j0 = r0j; d1 = r1d; j1 = r1j; d2 = r2d; j2 = r2j;                \
  }

// one kNN pair step (candidates 2k, 2k+1) on register state
#define KNN_PAIR(i)                                                            \
  {                                                                            \
    const float4 va = n_slab[(i)];                                             \
    float da = va.w + n_a2;                                                    \
    da = fmaf(va.x, n_ax, da); da = fmaf(va.y, n_ay, da); da = fmaf(va.z, n_az, da); \
    INSV(n_ta0, n_ta1, n_ta2, n_ja0, n_ja1, n_ja2, da, n_qbase + (i));         \
    const float4 vb = n_slab[(i) + 1];                                         \
    float db = vb.w + n_a2;                                                    \
    db = fmaf(vb.x, n_ax, db); db = fmaf(vb.y, n_ay, db); db = fmaf(vb.z, n_az, db); \
    INSV(n_tb0, n_tb1, n_tb2, n_jb0, n_jb1, n_jb2, db, n_qbase + (i) + 1);     \
  }

// ---------------- prep: W1,W2 fp32 -> bf16 ----------------
__global__ __launch_bounds__(256) void prep_w_kernel(
    const float* __restrict__ w1, const float* __restrict__ w2,
    unsigned short* __restrict__ w1b, unsigned short* __restrict__ w2b)
{
  const int i = blockIdx.x * 256 + threadIdx.x;
  const bool isW1 = i < 24576;
  const float4 v = isW1 ? ((const float4*)w1)[i] : ((const float4*)w2)[i - 24576];
  PK4 pk;
  pk.u[0] = f2bf(v.x); pk.u[1] = f2bf(v.y); pk.u[2] = f2bf(v.z); pk.u[3] = f2bf(v.w);
  if (isW1) ((uint2*)w1b)[i] = pk.q;
  else      ((uint2*)w2b)[i - 24576] = pk.q;
}

// ============ fg1 v5 (= r6 + knn-interleave + XCD swizzle) ============
// 512 threads (8 waves), 128 pts/block, grid 512. knn pair-steps run as VALU
// filler inside kt 0..2 (points1-only kts); merge at kt 3; gather kts 4..11
// use register-held pointers/weights. B via global_load_lds dbuf (r6 proven).
__global__ __launch_bounds__(512, 4) void fg1_kernel(
    const float* __restrict__ xyz1, const float* __restrict__ xyz2,
    const float* __restrict__ points1, const float* __restrict__ points2,
    const unsigned short* __restrict__ W1bf, const float* __restrict__ bias1,
    unsigned short* __restrict__ h1bf, float* __restrict__ sum1, float* __restrict__ sq1)
{
  __shared__ unsigned short sA[2][128][32];   // 16 KB (epilogue overlay)
  __shared__ unsigned short sB[2][256][32];   // 32 KB
  __shared__ float4 s2t[4 * 257];             // 16.45 KB

  const int tid = threadIdx.x;
  const int lane = tid & 63;
  const int wave = tid >> 6;

  // bijective XCD swizzle (512 = 8 XCD x 64): XCD x gets blocks x*64..x*64+63
  // -> contiguous point range -> 2 batches' points2 (2 MB) per XCD L2.
  const int bid = (int)(blockIdx.x & 7) * 64 + (int)(blockIdx.x >> 3);
  const int ptBase = bid * 128;
  const int b = ptBase >> 12;                 // 32 blocks per batch, no straddle

  const int fr = lane & 15;
  const int cs = lane >> 4;
  const int rdsh = ((cs ^ ((fr >> 1) & 3)) << 3);

  auto stageB = [&](int buf, int kt) {
    const int k0 = kt * 32;
#pragma unroll
    for (int c = 0; c < 2; ++c) {
      const int base = c * 512 + wave * 64;   // wave-uniform LDS chunk base
      const int s = base + lane;
      const int row = s >> 2, c16 = s & 3;
      const int ks = c16 ^ ((row >> 1) & 3);
      gl_lds16(W1bf + (size_t)row * NCIN + k0 + ks * 8,
               &sB[buf][0][0] + base * 8);
    }
  };

  // gather metadata (registers; set at kt==3 after the merge)
  const float* g0p = points2;
  const float* g1p = points2;
  const float* g2p = points2;
  float gw0 = 0.f, gw1 = 0.f, gw2 = 0.f;

  // A staging: thread = slot; row tid>>2 (same point as this thread's knn group)
  auto stageA = [&](int buf, int kt) {
    const int row = tid >> 2, c16 = tid & 3;
    const int ks = c16 ^ ((row >> 1) & 3);
    const int k = kt * 32 + ks * 8;
    PK8 pk;
    if (k < ND1) {                            // kt 0..3: cast points1
      const float* src = points1 + (size_t)(ptBase + row) * ND1 + k;
      const float4 va = ((const float4*)src)[0];
      const float4 vb = ((const float4*)src)[1];
      pk.u[0] = f2bf(va.x); pk.u[1] = f2bf(va.y); pk.u[2] = f2bf(va.z); pk.u[3] = f2bf(va.w);
      pk.u[4] = f2bf(vb.x); pk.u[5] = f2bf(vb.y); pk.u[6] = f2bf(vb.z); pk.u[7] = f2bf(vb.w);
    } else {                                  // kt 4..11: 3-NN gather + combine
      const int ko = k - ND1;
      const float4* r0 = (const float4*)(g0p + ko);
      const float4* r1 = (const float4*)(g1p + ko);
      const float4* r2 = (const float4*)(g2p + ko);
#pragma unroll
      for (int h = 0; h < 2; ++h) {
        const float4 va = r0[h], vb = r1[h], vc = r2[h];
        pk.u[h * 4 + 0] = f2bf(gw0 * va.x + gw1 * vb.x + gw2 * vc.x);
        pk.u[h * 4 + 1] = f2bf(gw0 * va.y + gw1 * vb.y + gw2 * vc.y);
        pk.u[h * 4 + 2] = f2bf(gw0 * va.z + gw1 * vb.z + gw2 * vc.z);
        pk.u[h * 4 + 3] = f2bf(gw0 * va.w + gw1 * vb.w + gw2 * vc.w);
      }
    }
    *(uint4*)(&sA[buf][0][0] + tid * 8) = pk.q;
  };

  // ---- knn register state (this thread: point tid>>2, quarter tid&3) ----
  const int ptl = tid >> 2;
  const float n_ax = xyz1[(size_t)(ptBase + ptl) * 3 + 0];
  const float n_ay = xyz1[(size_t)(ptBase + ptl) * 3 + 1];
  const float n_az = xyz1[(size_t)(ptBase + ptl) * 3 + 2];
  const float n_a2 = n_ax * n_ax + n_ay * n_ay + n_az * n_az;
  const float4* n_slab = &s2t[(tid & 3) * 257];
  const int n_qbase = (tid & 3) * 256;
  const float INF = 3.4e38f;
  float n_ta0 = INF, n_ta1 = INF, n_ta2 = INF;
  float n_tb0 = INF, n_tb1 = INF, n_tb2 = INF;
  int n_ja0 = 0, n_ja1 = 0, n_ja2 = 0, n_jb0 = 0, n_jb1 = 0, n_jb2 = 0;

  // ---- prologue: prefetch B0, stage s2t, stage A0 (points1) ----
  stageB(0, 0);
  if (tid < 256) {
    const float* src = xyz2 + (size_t)b * NSRC * 3 + tid * 12;
    const float4 l0 = ((const float4*)src)[0];
    const float4 l1 = ((const float4*)src)[1];
    const float4 l2 = ((const float4*)src)[2];
    const float xs[4] = {l0.x, l0.w, l1.z, l2.y};
    const float ys[4] = {l0.y, l1.x, l1.w, l2.z};
    const float zs[4] = {l0.z, l1.y, l2.x, l2.w};
    const int qq = tid >> 6;
    const int ibase = (tid & 63) * 4;
#pragma unroll
    for (int u = 0; u < 4; ++u) {
      const float c = xs[u] * xs[u] + ys[u] * ys[u] + zs[u] * zs[u];
      float4 v;
      v.x = -2.0f * xs[u]; v.y = -2.0f * ys[u]; v.z = -2.0f * zs[u]; v.w = c;
      s2t[qq * 257 + ibase + u] = v;
    }
  }
  stageA(0, 0);
  __syncthreads();

  // ---- K-loop with knn slices as latency filler ----
  f32x4 acc[16];
#pragma unroll
  for (int j = 0; j < 16; ++j)
#pragma unroll
    for (int q = 0; q < 4; ++q) acc[j][q] = 0.0f;

  int ki = 0;
  int buf = 0;
  for (int kt = 0; kt < 12; ++kt) {
    if (kt < 11) stageB(buf ^ 1, kt + 1);
    if (kt < 3) {                             // knn slices: 43+43+42 = 128 pairs
      const int take = (kt < 2) ? 43 : 42;
      for (int u = 0; u < take; ++u, ++ki) KNN_PAIR(2 * ki);
    } else if (kt == 3) {                     // merge -> gather regs (all lanes)
      MERGE3(n_ta0, n_ja0, n_ta1, n_ja1, n_ta2, n_ja2,
             n_tb0, n_jb0, n_tb1, n_jb1, n_tb2, n_jb2);
#pragma unroll
      for (int m = 1; m <= 2; m <<= 1) {
        float e0 = __shfl_xor(n_ta0, m), e1 = __shfl_xor(n_ta1, m), e2 = __shfl_xor(n_ta2, m);
        int i0 = __shfl_xor(n_ja0, m), i1 = __shfl_xor(n_ja1, m), i2 = __shfl_xor(n_ja2, m);
        MERGE3(n_ta0, n_ja0, n_ta1, n_ja1, n_ta2, n_ja2, e0, i0, e1, i1, e2, i2);
      }
      float w0 = 1.f / (n_ta0 + 1e-8f), w1 = 1.f / (n_ta1 + 1e-8f), w2 = 1.f / (n_ta2 + 1e-8f);
      const float inv = 1.f / (w0 + w1 + w2);
      gw0 = w0 * inv; gw1 = w1 * inv; gw2 = w2 * inv;
      const float* p2base = points2 + (size_t)b * NSRC * ND2;
      g0p = p2base + (size_t)n_ja0 * ND2;
      g1p = p2base + (size_t)n_ja1 * ND2;
      g2p = p2base + (size_t)n_ja2 * ND2;
    }
    if (kt < 11) stageA(buf ^ 1, kt + 1);
    const bf16x8 a = *(const bf16x8*)&sA[buf][wave * 16 + fr][rdsh];
#pragma unroll
    for (int j = 0; j < 16; ++j) {
      const bf16x8 bv = *(const bf16x8*)&sB[buf][j * 16 + fr][rdsh];
      acc[j] = __builtin_amdgcn_mfma_f32_16x16x32_bf16(a, bv, acc[j], 0, 0, 0);
    }
    __syncthreads();
    buf ^= 1;
  }

  // ---- epilogue: h1bf store + BN1 partial sums (r6 verbatim) ----
  float* redS = (float*)&sA[0][0][0];         // 8 KB overlay
  float* redQ = redS + 2048;                  // next 8 KB
  const int r0 = cs * 4;
#pragma unroll
  for (int j = 0; j < 16; ++j) {
    const int ch = j * 16 + fr;
    const float bb = bias1[ch];
    float s = 0.f, s2 = 0.f;
#pragma unroll
    for (int q = 0; q < 4; ++q) {
      const int pt = ptBase + wave * 16 + r0 + q;
      const float v = acc[j][q] + bb;
      h1bf[(size_t)pt * NCMID + ch] = f2bf(v);
      s += v; s2 += v * v;
    }
    s += __shfl_xor(s, 16);  s2 += __shfl_xor(s2, 16);
    s += __shfl_xor(s, 32);  s2 += __shfl_xor(s2, 32);
    if (cs == 0) { redS[wave * 256 + ch] = s; redQ[wave * 256 + ch] = s2; }
  }
  __syncthreads();
  if (tid < NCMID) {
    float s = 0.f, s2 = 0.f;
#pragma unroll
    for (int w = 0; w < 8; ++w) {
      s  += redS[w * 256 + tid];
      s2 += redQ[w * 256 + tid];
    }
    atomicAdd(&sum1[tid], s);
    atomicAdd(&sq1[tid], s2);
  }
}

// ---------------- fold BN into per-channel affine: y = a*x + d ----------------
template <int C>
__global__ void stats_kernel(const float* __restrict__ sum, const float* __restrict__ sumsq,
                             const float* __restrict__ g, const float* __restrict__ be,
                             float* __restrict__ a, float* __restrict__ d)
{
  const int c = threadIdx.x;
  const float mean = sum[c] * (1.0f / BNTOT);
  const float var = sumsq[c] * (1.0f / BNTOT) - mean * mean;
  const float inv = rsqrtf(var + BN_EPS);
  const float ac = g[c] * inv;
  a[c] = ac;
  d[c] = be[c] - mean * ac;
}

// ---------------- GEMM2 (+fused BN2 column sums, bf16 out) — proven r5/r6 ----------------
__global__ __launch_bounds__(256, 2) void gemm2_kernel(
    const unsigned short* __restrict__ h1bf, const unsigned short* __restrict__ W2bf,
    const float* __restrict__ bias2, const float* __restrict__ aff_a,
    const float* __restrict__ aff_d, unsigned short* __restrict__ h2bf,
    float* __restrict__ sum2, float* __restrict__ sq2)
{
  __shared__ unsigned short sA[2][128][32];
  __shared__ unsigned short sB[2][128][32];
  __shared__ float sa[NCMID], sd[NCMID];
  const int tid = threadIdx.x;
  const int lane = tid & 63;
  const int wave = tid >> 6;
  const int ptBase = blockIdx.x * 128;
  sa[tid] = aff_a[tid];
  sd[tid] = aff_d[tid];

  f32x4 acc[2][8];
#pragma unroll
  for (int m = 0; m < 2; ++m)
#pragma unroll
    for (int j = 0; j < 8; ++j)
#pragma unroll
      for (int q = 0; q < 4; ++q) acc[m][j][q] = 0.0f;

  const int fr = lane & 15;
  const int cs = lane >> 4;
  const int rdsh = ((cs ^ ((fr >> 1) & 3)) << 3);

  auto stageB = [&](int buf, int kt) {
    const int k0 = kt * 32;
#pragma unroll
    for (int c = 0; c < 2; ++c) {
      const int s = c * 256 + wave * 64 + lane;
      const int row = s >> 2, c16 = s & 3;
      const int ks = c16 ^ ((row >> 1) & 3);
      gl_lds16(W2bf + (size_t)row * NCMID + k0 + ks * 8,
               &sB[buf][0][0] + (c * 256 + wave * 64) * 8);
    }
  };
  auto stageA = [&](int buf, int kt) {
    const int k0 = kt * 32;
#pragma unroll
    for (int c = 0; c < 2; ++c) {
      const int s = c * 256 + tid;
      const int row = s >> 2, c16 = s & 3;
      const int ks = c16 ^ ((row >> 1) & 3);
      const int k = k0 + ks * 8;
      PK8 v;
      v.q = *(const uint4*)(h1bf + (size_t)(ptBase + row) * NCMID + k);
      PK8 pk;
#pragma unroll
      for (int j = 0; j < 8; ++j)
        pk.u[j] = f2bf(fmaxf(0.f, sa[k + j] * bf2f(v.u[j]) + sd[k + j]));
      *(uint4*)(&sA[buf][0][0] + s * 8) = pk.q;
    }
  };

  stageB(0, 0);
  __syncthreads();
  stageA(0, 0);
  __syncthreads();
  int cur = 0;
  for (int kt = 0; kt < 8; ++kt) {
    if (kt < 7) { stageB(cur ^ 1, kt + 1); stageA(cur ^ 1, kt + 1); }
    const bf16x8 a0 = *(const bf16x8*)&sA[cur][wave * 32 + fr][rdsh];
    const bf16x8 a1 = *(const bf16x8*)&sA[cur][wave * 32 + 16 + fr][rdsh];
#pragma unroll
    for (int j = 0; j < 8; ++j) {
      const bf16x8 b = *(const bf16x8*)&sB[cur][j * 16 + fr][rdsh];
      acc[0][j] = __builtin_amdgcn_mfma_f32_16x16x32_bf16(a0, b, acc[0][j], 0, 0, 0);
      acc[1][j] = __builtin_amdgcn_mfma_f32_16x16x32_bf16(a1, b, acc[1][j], 0, 0, 0);
    }
    __syncthreads();
    cur ^= 1;
  }

  float* redS = (float*)&sA[0][0][0];
  float* redQ = redS + 512;
  const int col = fr;
  const int r0 = cs * 4;
#pragma unroll
  for (int j = 0; j < 8; ++j) {
    const int ch = j * 16 + col;
    const float bb = bias2[ch];
    float s = 0.f, s2 = 0.f;
#pragma unroll
    for (int m = 0; m < 2; ++m)
#pragma unroll
      for (int q = 0; q < 4; ++q) {
        const int pt = ptBase + wave * 32 + m * 16 + r0 + q;
        const float v = acc[m][j][q] + bb;
        h2bf[(size_t)pt * NCOUT + ch] = f2bf(v);
        s += v; s2 += v * v;
      }
    s += __shfl_xor(s, 16);  s2 += __shfl_xor(s2, 16);
    s += __shfl_xor(s, 32);  s2 += __shfl_xor(s2, 32);
    if (cs == 0) { redS[wave * 128 + fr * 8 + j] = s; redQ[wave * 128 + fr * 8 + j] = s2; }
  }
  __syncthreads();
  if (tid < NCOUT) {
    const int ch = tid;
    const int f = ch & 15, j = ch >> 4;
    float s = 0.f, s2 = 0.f;
#pragma unroll
    for (int w = 0; w < 4; ++w) {
      s  += redS[w * 128 + f * 8 + j];
      s2 += redQ[w * 128 + f * 8 + j];
    }
    atomicAdd(&sum2[ch], s);
    atomicAdd(&sq2[ch], s2);
  }
}

// ---------------- final: BN2-affine + ReLU, bf16 h2 -> fp32 out ----------------
__global__ __launch_bounds__(256) void final_kernel(
    const unsigned short* __restrict__ h2bf, float* __restrict__ out,
    const float* __restrict__ a2, const float* __restrict__ d2)
{
  __shared__ float sa[NCOUT], sd[NCOUT];
  if (threadIdx.x < NCOUT) { sa[threadIdx.x] = a2[threadIdx.x]; sd[threadIdx.x] = d2[threadIdx.x]; }
  __syncthreads();
  const int total8 = BNTOT * NCOUT / 8;
  for (int i = blockIdx.x * blockDim.x + threadIdx.x; i < total8;
       i += gridDim.x * blockDim.x) {
    PK8 v; v.q = ((const uint4*)h2bf)[i];
    const int c = (i & 15) * 8;
    float4 o0, o1;
    o0.x = fmaxf(0.f, sa[c + 0] * bf2f(v.u[0]) + sd[c + 0]);
    o0.y = fmaxf(0.f, sa[c + 1] * bf2f(v.u[1]) + sd[c + 1]);
    o0.z = fmaxf(0.f, sa[c + 2] * bf2f(v.u[2]) + sd[c + 2]);
    o0.w = fmaxf(0.f, sa[c + 3] * bf2f(v.u[3]) + sd[c + 3]);
    o1.x = fmaxf(0.f, sa[c + 4] * bf2f(v.u[4]) + sd[c + 4]);
    o1.y = fmaxf(0.f, sa[c + 5] * bf2f(v.u[5]) + sd[c + 5]);
    o1.z = fmaxf(0.f, sa[c + 6] * bf2f(v.u[6]) + sd[c + 6]);
    o1.w = fmaxf(0.f, sa[c + 7] * bf2f(v.u[7]) + sd[c + 7]);
    ((float4*)out)[i * 2]     = o0;
    ((float4*)out)[i * 2 + 1] = o1;
  }
}

extern "C" void kernel_launch(void* const* d_in, const int* in_sizes, int n_in,
                              void* d_out, int out_size, void* d_ws, size_t ws_size,
                              hipStream_t stream) {
  const float* xyz1    = (const float*)d_in[0];
  const float* xyz2    = (const float*)d_in[1];
  const float* points1 = (const float*)d_in[2];
  const float* points2 = (const float*)d_in[3];
  const float* W1      = (const float*)d_in[4];
  const float* b1      = (const float*)d_in[5];
  const float* g1      = (const float*)d_in[6];
  const float* be1     = (const float*)d_in[7];
  const float* W2      = (const float*)d_in[8];
  const float* b2      = (const float*)d_in[9];
  const float* g2      = (const float*)d_in[10];
  const float* be2     = (const float*)d_in[11];
  float* out = (float*)d_out;

  char* ws = (char*)d_ws;
  const size_t h1_bytes  = (size_t)BNTOT * NCMID * 2;    // 32 MB
  const size_t h2_bytes  = (size_t)BNTOT * NCOUT * 2;    // 16 MB
  const size_t w1b_bytes = (size_t)NCMID * NCIN * 2;     // 192 KB
  const size_t w2b_bytes = (size_t)NCOUT * NCMID * 2;    // 64 KB
  unsigned short* h1bf = (unsigned short*)ws;
  unsigned short* h2bf = (unsigned short*)(ws + h1_bytes);
  unsigned short* W1bf = (unsigned short*)(ws + h1_bytes + h2_bytes);
  unsigned short* W2bf = (unsigned short*)(ws + h1_bytes + h2_bytes + w1b_bytes);
  float* stats = (float*)(ws + h1_bytes + h2_bytes + w1b_bytes + w2b_bytes);
  float* sum1 = stats;
  float* sq1  = stats + 256;
  float* sum2 = stats + 512;
  float* sq2  = stats + 640;
  float* a1   = stats + 768;
  float* dd1  = stats + 1024;
  float* a2v  = stats + 1280;
  float* dd2v = stats + 1408;

  hipMemsetAsync(stats, 0, 768 * sizeof(float), stream);

  prep_w_kernel<<<128, 256, 0, stream>>>(W1, W2, W1bf, W2bf);
  fg1_kernel<<<BNTOT / 128, 512, 0, stream>>>(xyz1, xyz2, points1, points2,
                                              W1bf, b1, h1bf, sum1, sq1);
  stats_kernel<NCMID><<<1, NCMID, 0, stream>>>(sum1, sq1, g1, be1, a1, dd1);
  gemm2_kernel<<<BNTOT / 128, 256, 0, stream>>>(h1bf, W2bf, b2, a1, dd1, h2bf, sum2, sq2);
  stats_kernel<NCOUT><<<1, NCOUT, 0, stream>>>(sum2, sq2, g2, be2, a2v, dd2v);
  final_kernel<<<2048, 256, 0, stream>>>(h2bf, out, a2v, dd2v);
}